// Round 1
// baseline (1556.928 us; speedup 1.0000x reference)
//
#include <hip/hip_runtime.h>

// Problem constants (fixed by setup_inputs)
#define NVEL  400              // v is 400x400
#define PMLW  20
#define NSIDE 440              // padded domain = NVEL + 2*PML
#define NPAD  444              // +2 zero ring each side for stencil
#define NPP   (NPAD*NPAD)      // 197136 floats per field slice
#define POFF  (2*NPAD + 2)     // offset of (0,0) interior point
#define BATCH 4
#define NT    100
#define NREC  100

__device__ __forceinline__ int fidx(int b, int y, int x) {
    return b*NPP + POFF + y*NPAD + x;
}

// Build v2dt2 (edge-padded velocity squared * dt^2) and PML profiles.
__global__ __launch_bounds__(256) void kSetup(
    const float* __restrict__ v, float* __restrict__ v2,
    float* __restrict__ prof_a, float* __restrict__ prof_b)
{
    int i = blockIdx.x*256 + threadIdx.x;
    if (i < NSIDE*NSIDE) {
        int y = i / NSIDE, x = i - y*NSIDE;
        int cy = min(max(y - PMLW, 0), NVEL-1);
        int cx = min(max(x - PMLW, 0), NVEL-1);
        float vv = v[cy*NVEL + cx];
        v2[POFF + y*NPAD + x] = vv*vv*(float)(0.0008*0.0008);
    }
    if (i < NSIDE) {
        float xi = (float)i;
        float dl = fminf(fmaxf((20.0f - xi) / 20.0f, 0.0f), 1.0f);
        float dr = fminf(fmaxf((xi - 419.0f) / 20.0f, 0.0f), 1.0f);
        float d  = fmaxf(dl, dr);
        const float smax = (float)(3.0*2600.0*6.907755278982137/160.0); // 3*vmax*ln(1000)/(2*pml*dh)
        float sg = smax*d*d;
        float bb = expf(-sg*0.0008f);
        prof_b[i] = bb;
        prof_a[i] = bb - 1.0f;
    }
}

// Kernel A: psi updates (needs only wfc). Also records receivers of the
// PREVIOUS step (wfc is the previous wfp) using the first 400 global threads.
__global__ __launch_bounds__(256) void kA(
    const float* __restrict__ wfc,
    float* __restrict__ psiy, float* __restrict__ psix,
    const float* __restrict__ prof_a, const float* __restrict__ prof_b,
    float* __restrict__ rec_out, const int* __restrict__ rloc, int t)
{
    int x = blockIdx.x*64 + threadIdx.x;
    int y = blockIdx.y*4  + threadIdx.y;
    int b = blockIdx.z;

    if (t > 0) {
        int gid = ((b*gridDim.y + blockIdx.y)*gridDim.x + blockIdx.x)*256
                  + threadIdx.y*64 + threadIdx.x;
        if (gid < BATCH*NREC) {
            int rb = gid / NREC;
            int ry = rloc[gid*2]   + PMLW;
            int rx = rloc[gid*2+1] + PMLW;
            rec_out[gid*NT + (t-1)] = wfc[fidx(rb, ry, rx)];
        }
    }
    if (x >= NSIDE) return;

    const float* wc = wfc + b*NPP + POFF;
    int idx = y*NPAD + x;
    const float C1 = 1.0f/48.0f;  // 1/(12*dh), dh=4
    float d1y = (wc[idx-2*NPAD] - wc[idx+2*NPAD] + 8.0f*(wc[idx+NPAD] - wc[idx-NPAD])) * C1;
    float d1x = (wc[idx-2]      - wc[idx+2]      + 8.0f*(wc[idx+1]    - wc[idx-1]   )) * C1;
    int g = b*NPP + POFF + idx;
    psiy[g] = prof_b[y]*psiy[g] + prof_a[y]*d1y;
    psix[g] = prof_b[x]*psix[g] + prof_a[x]*d1x;
}

// Kernel B: d2 + d1(psi), zeta updates, wfp (written over wfm in place),
// fused source injection.
__global__ __launch_bounds__(256) void kB(
    const float* __restrict__ wfc, float* __restrict__ wfm_p,
    const float* __restrict__ psiy, const float* __restrict__ psix,
    float* __restrict__ zetay, float* __restrict__ zetax,
    const float* __restrict__ v2,
    const float* __restrict__ prof_a, const float* __restrict__ prof_b,
    const float* __restrict__ amp, const int* __restrict__ sloc, int t)
{
    int x = blockIdx.x*64 + threadIdx.x;
    int y = blockIdx.y*4  + threadIdx.y;
    int b = blockIdx.z;
    if (x >= NSIDE) return;

    int idx = y*NPAD + x;
    const float* wc = wfc  + b*NPP + POFF;
    const float* py = psiy + b*NPP + POFF;
    const float* px = psix + b*NPP + POFF;
    const float C1 = 1.0f/48.0f;   // 1/(12*dh)
    const float C2 = 1.0f/192.0f;  // 1/(12*dh*dh)

    float d2y = (-(wc[idx-2*NPAD] + wc[idx+2*NPAD]) + 16.0f*(wc[idx+NPAD] + wc[idx-NPAD]) - 30.0f*wc[idx]) * C2
              + (py[idx-2*NPAD] - py[idx+2*NPAD] + 8.0f*(py[idx+NPAD] - py[idx-NPAD])) * C1;
    float d2x = (-(wc[idx-2] + wc[idx+2]) + 16.0f*(wc[idx+1] + wc[idx-1]) - 30.0f*wc[idx]) * C2
              + (px[idx-2] - px[idx+2] + 8.0f*(px[idx+1] - px[idx-1])) * C1;

    int g = b*NPP + POFF + idx;
    float ayv = prof_a[y], byv = prof_b[y];
    float axv = prof_a[x], bxv = prof_b[x];
    float zy = byv*zetay[g] + ayv*d2y;
    float zx = bxv*zetax[g] + axv*d2x;
    zetay[g] = zy;
    zetax[g] = zx;

    float vv = v2[POFF + idx];
    float wnew = vv*(d2y + zy + d2x + zx) + 2.0f*wc[idx] - wfm_p[g];

    int sy = sloc[b*2]   + PMLW;
    int sx = sloc[b*2+1] + PMLW;
    if (y == sy && x == sx) wnew += vv * amp[b*NT + t];

    wfm_p[g] = wnew;   // ping-pong: wfp overwrites old wfm
}

// Record the final step's receivers.
__global__ __launch_bounds__(256) void kFinal(
    const float* __restrict__ wf, float* __restrict__ rec_out,
    const int* __restrict__ rloc)
{
    int i = blockIdx.x*256 + threadIdx.x;
    if (i < BATCH*NREC) {
        int b = i / NREC;
        int ry = rloc[i*2]   + PMLW;
        int rx = rloc[i*2+1] + PMLW;
        rec_out[i*NT + (NT-1)] = wf[fidx(b, ry, rx)];
    }
}

extern "C" void kernel_launch(void* const* d_in, const int* in_sizes, int n_in,
                              void* d_out, int out_size, void* d_ws, size_t ws_size,
                              hipStream_t stream) {
    const float* v    = (const float*)d_in[0];
    const float* amp  = (const float*)d_in[1];
    const int*   sloc = (const int*)d_in[2];
    const int*   rloc = (const int*)d_in[3];
    float* out = (float*)d_out;

    float* ws = (float*)d_ws;
    const size_t S = (size_t)BATCH * NPP;   // floats per field
    float* wfA    = ws;
    float* wfB    = ws + 1*S;
    float* psiy   = ws + 2*S;
    float* psix   = ws + 3*S;
    float* zetay  = ws + 4*S;
    float* zetax  = ws + 5*S;
    float* v2     = ws + 6*S;
    float* prof_a = v2 + NPP;
    float* prof_b = prof_a + NSIDE;

    // Zero all six state fields (incl. their zero rings) in one memset.
    hipMemsetAsync(ws, 0, 6*S*sizeof(float), stream);

    // v2dt2 + PML profiles
    kSetup<<<(NSIDE*NSIDE + 255)/256, 256, 0, stream>>>(v, v2, prof_a, prof_b);

    dim3 grid((NSIDE + 63)/64, NSIDE/4, BATCH);  // (7, 110, 4)
    dim3 block(64, 4, 1);

    float* wfc = wfA;
    float* wfm = wfB;
    for (int t = 0; t < NT; ++t) {
        kA<<<grid, block, 0, stream>>>(wfc, psiy, psix, prof_a, prof_b, out, rloc, t);
        kB<<<grid, block, 0, stream>>>(wfc, wfm, psiy, psix, zetay, zetax,
                                       v2, prof_a, prof_b, amp, sloc, t);
        float* tmp = wfc; wfc = wfm; wfm = tmp;
    }
    kFinal<<<2, 256, 0, stream>>>(wfc, out, rloc);
}

// Round 2
// 1449.341 us; speedup vs baseline: 1.0742x; 1.0742x over previous
//
#include <hip/hip_runtime.h>

// Problem constants (fixed by setup_inputs)
#define NVEL  400              // v is 400x400
#define PMLW  20
#define NSIDE 440              // padded domain = NVEL + 2*PML
#define RING  4                // zero ring (stencil halo 2 + tile-overshoot clamp)
#define NPAD  448              // NSIDE + 2*RING
#define NPP   (NPAD*NPAD)      // floats per field slice
#define POFF  (RING*NPAD + RING)
#define BATCH 4
#define NT    100
#define NREC  100

// Tile geometry: 64x16 interior per block, 256 threads, 4 cells/thread.
#define TX 64
#define TY 16
#define HW 4                   // wf halo in LDS
#define HP 2                   // psi halo in LDS
#define LWX (TX+2*HW)          // 72
#define LWY (TY+2*HW)          // 24
#define LPYY (TY+2*HP)         // 20  (psiy: y-halo only)
#define LPXX (TX+2*HP)         // 68  (psix: x-halo only)

__global__ __launch_bounds__(256) void kSetup(
    const float* __restrict__ v, float* __restrict__ v2,
    float* __restrict__ prof_a, float* __restrict__ prof_b)
{
    int i = blockIdx.x*256 + threadIdx.x;
    if (i < NSIDE*NSIDE) {
        int y = i / NSIDE, x = i - y*NSIDE;
        int cy = min(max(y - PMLW, 0), NVEL-1);
        int cx = min(max(x - PMLW, 0), NVEL-1);
        float vv = v[cy*NVEL + cx];
        v2[POFF + y*NPAD + x] = vv*vv*(float)(0.0008*0.0008);
    }
    if (i < NSIDE) {
        float xi = (float)i;
        float dl = fminf(fmaxf((20.0f - xi) / 20.0f, 0.0f), 1.0f);
        float dr = fminf(fmaxf((xi - 419.0f) / 20.0f, 0.0f), 1.0f);
        float d  = fmaxf(dl, dr);
        const float smax = (float)(3.0*2600.0*6.907755278982137/160.0);
        float sg = smax*d*d;
        float bb = expf(-sg*0.0008f);
        prof_b[i] = bb;
        prof_a[i] = bb - 1.0f;
    }
}

// Fully fused step: psi update (recomputed in +2 halo from LDS-staged wfc),
// then d2/zeta/wfp update for the block interior. One kernel per time step.
__global__ __launch_bounds__(256) void kStep(
    const float* __restrict__ wfc, float* __restrict__ wfn,
    const float* __restrict__ psiy_r, float* __restrict__ psiy_w,
    const float* __restrict__ psix_r, float* __restrict__ psix_w,
    float* __restrict__ zetay, float* __restrict__ zetax,
    const float* __restrict__ v2,
    const float* __restrict__ prof_a, const float* __restrict__ prof_b,
    const float* __restrict__ amp, const int* __restrict__ sloc,
    float* __restrict__ rec_out, const int* __restrict__ rloc, int t)
{
    __shared__ float s_wf[LWY][LWX];
    __shared__ float s_py[LPYY][TX];
    __shared__ float s_px[TY][LPXX];

    const int tx = threadIdx.x, ty = threadIdx.y;
    const int tid = ty*64 + tx;
    const int bx0 = blockIdx.x*TX, by0 = blockIdx.y*TY;
    const int b = blockIdx.z;
    const float* wcb = wfc + b*NPP + POFF;
    const float C1 = 1.0f/48.0f;   // 1/(12*dh)
    const float C2 = 1.0f/192.0f;  // 1/(12*dh*dh)

    // Record receivers of the previous step's output (wfc == wfp at t-1).
    if (t > 0) {
        int gid = ((b*gridDim.y + blockIdx.y)*gridDim.x + blockIdx.x)*256 + tid;
        if (gid < BATCH*NREC) {
            int rb = gid / NREC;
            int ry = rloc[gid*2]   + PMLW;
            int rx = rloc[gid*2+1] + PMLW;
            rec_out[gid*NT + (t-1)] = wfc[rb*NPP + POFF + ry*NPAD + rx];
        }
    }

    // Stage wfc tile + 4-halo. Clamp into the zero ring for edge overshoot.
    for (int i = tid; i < LWY*LWX; i += 256) {
        int ly = i / LWX, lx = i - ly*LWX;
        int gy = min(by0 - HW + ly, NSIDE-1+RING);
        int gx = min(bx0 - HW + lx, NSIDE-1+RING);
        s_wf[ly][lx] = wcb[gy*NPAD + gx];
    }
    __syncthreads();

    // psiy on [0,TX) x [-HP, TY+HP): needs d1y(wfc). Outside-domain psi == 0.
    for (int i = tid; i < LPYY*TX; i += 256) {
        int ly = i >> 6, lx = i & 63;
        int gy = by0 - HP + ly, gx = bx0 + lx;
        int wy = ly + (HW-HP), wx = lx + HW;
        float d1 = (s_wf[wy-2][wx] - s_wf[wy+2][wx]
                    + 8.0f*(s_wf[wy+1][wx] - s_wf[wy-1][wx])) * C1;
        float val = 0.0f;
        if (gy >= 0 && gy < NSIDE && gx < NSIDE) {
            float old = psiy_r[b*NPP + POFF + gy*NPAD + gx];
            val = prof_b[gy]*old + prof_a[gy]*d1;
            if (ly >= HP && ly < TY+HP)
                psiy_w[b*NPP + POFF + gy*NPAD + gx] = val;
        }
        s_py[ly][lx] = val;
    }

    // psix on [-HP,TX+HP) x [0,TY): needs d1x(wfc).
    for (int i = tid; i < TY*LPXX; i += 256) {
        int ly = i / LPXX, lx = i - ly*LPXX;
        int gy = by0 + ly, gx = bx0 - HP + lx;
        int wy = ly + HW, wx = lx + (HW-HP);
        float d1 = (s_wf[wy][wx-2] - s_wf[wy][wx+2]
                    + 8.0f*(s_wf[wy][wx+1] - s_wf[wy][wx-1])) * C1;
        float val = 0.0f;
        if (gx >= 0 && gx < NSIDE && gy < NSIDE) {
            float old = psix_r[b*NPP + POFF + gy*NPAD + gx];
            val = prof_b[gx]*old + prof_a[gx]*d1;
            if (lx >= HP && lx < TX+HP)
                psix_w[b*NPP + POFF + gy*NPAD + gx] = val;
        }
        s_px[ly][lx] = val;
    }
    __syncthreads();

    // Interior update: 4 rows per thread (ty, ty+4, ty+8, ty+12).
    int sy = sloc[b*2]   + PMLW;
    int sx = sloc[b*2+1] + PMLW;
    int gx = bx0 + tx;
    if (gx < NSIDE) {
        #pragma unroll
        for (int k = 0; k < 4; ++k) {
            int ly = ty + 4*k;
            int gy = by0 + ly;
            if (gy >= NSIDE) continue;
            int wy = ly + HW, wx = tx + HW;
            float d2y = (-(s_wf[wy-2][wx] + s_wf[wy+2][wx])
                         + 16.0f*(s_wf[wy-1][wx] + s_wf[wy+1][wx])
                         - 30.0f*s_wf[wy][wx]) * C2
                      + (s_py[ly+HP-2][tx] - s_py[ly+HP+2][tx]
                         + 8.0f*(s_py[ly+HP+1][tx] - s_py[ly+HP-1][tx])) * C1;
            float d2x = (-(s_wf[wy][wx-2] + s_wf[wy][wx+2])
                         + 16.0f*(s_wf[wy][wx-1] + s_wf[wy][wx+1])
                         - 30.0f*s_wf[wy][wx]) * C2
                      + (s_px[ly][tx+HP-2] - s_px[ly][tx+HP+2]
                         + 8.0f*(s_px[ly][tx+HP+1] - s_px[ly][tx+HP-1])) * C1;
            int g = b*NPP + POFF + gy*NPAD + gx;
            float zy = prof_b[gy]*zetay[g] + prof_a[gy]*d2y;
            float zx = prof_b[gx]*zetax[g] + prof_a[gx]*d2x;
            zetay[g] = zy;
            zetax[g] = zx;
            float vv = v2[POFF + gy*NPAD + gx];
            float wnew = vv*(d2y + zy + d2x + zx) + 2.0f*s_wf[wy][wx] - wfn[g];
            if (gy == sy && gx == sx) wnew += vv * amp[b*NT + t];
            wfn[g] = wnew;
        }
    }
}

__global__ __launch_bounds__(256) void kFinal(
    const float* __restrict__ wf, float* __restrict__ rec_out,
    const int* __restrict__ rloc)
{
    int i = blockIdx.x*256 + threadIdx.x;
    if (i < BATCH*NREC) {
        int b = i / NREC;
        int ry = rloc[i*2]   + PMLW;
        int rx = rloc[i*2+1] + PMLW;
        rec_out[i*NT + (NT-1)] = wf[b*NPP + POFF + ry*NPAD + rx];
    }
}

extern "C" void kernel_launch(void* const* d_in, const int* in_sizes, int n_in,
                              void* d_out, int out_size, void* d_ws, size_t ws_size,
                              hipStream_t stream) {
    const float* v    = (const float*)d_in[0];
    const float* amp  = (const float*)d_in[1];
    const int*   sloc = (const int*)d_in[2];
    const int*   rloc = (const int*)d_in[3];
    float* out = (float*)d_out;

    float* ws = (float*)d_ws;
    const size_t S = (size_t)BATCH * NPP;
    float* wfA    = ws;
    float* wfB    = ws + 1*S;
    float* psiyA  = ws + 2*S;
    float* psiyB  = ws + 3*S;
    float* psixA  = ws + 4*S;
    float* psixB  = ws + 5*S;
    float* zetay  = ws + 6*S;
    float* zetax  = ws + 7*S;
    float* v2     = ws + 8*S;
    float* prof_a = v2 + NPP;
    float* prof_b = prof_a + NSIDE;

    // Zero the 8 state fields (incl. rings) in one memset.
    hipMemsetAsync(ws, 0, 8*S*sizeof(float), stream);

    kSetup<<<(NSIDE*NSIDE + 255)/256, 256, 0, stream>>>(v, v2, prof_a, prof_b);

    dim3 grid((NSIDE + TX - 1)/TX, (NSIDE + TY - 1)/TY, BATCH);  // (7, 28, 4)
    dim3 block(64, 4, 1);

    float* wfc = wfA;  float* wfn = wfB;
    float* pyr = psiyA; float* pyw = psiyB;
    float* pxr = psixA; float* pxw = psixB;
    for (int t = 0; t < NT; ++t) {
        kStep<<<grid, block, 0, stream>>>(wfc, wfn, pyr, pyw, pxr, pxw,
                                          zetay, zetax, v2, prof_a, prof_b,
                                          amp, sloc, out, rloc, t);
        float* tmp;
        tmp = wfc; wfc = wfn; wfn = tmp;
        tmp = pyr; pyr = pyw; pyw = tmp;
        tmp = pxr; pxr = pxw; pxw = tmp;
    }
    kFinal<<<2, 256, 0, stream>>>(wfc, out, rloc);
}

// Round 3
// 1393.723 us; speedup vs baseline: 1.1171x; 1.0399x over previous
//
#include <hip/hip_runtime.h>

#define NVEL  400
#define PMLW  20
#define NSIDE 440
#define BATCH 4
#define NT    100
#define NREC  100

#define TS 55            // tile side; 8x8 tiles x 4 batches = 256 blocks (1/CU)
#define GT 8
#define WP 64            // wf LDS pitch (rows/cols -4..58 => 63, padded to 64)
#define PYP 56           // psiy pitch (rows -2..56 x cols 0..54)
#define PXP 60           // psix pitch (rows 0..54 x cols -2..56)
#define ZP 56            // zeta / v2 pitch

#define C1f (1.0f/48.0f)    // 1/(12*dh)
#define C2f (1.0f/192.0f)   // 1/(12*dh*dh)

#define NTH 1024

__global__ __launch_bounds__(NTH, 1) void kWave(
    const float* __restrict__ v, const float* __restrict__ amp,
    const int* __restrict__ sloc, const int* __restrict__ rloc,
    float* __restrict__ out, int* flags, float* strips)
{
    __shared__ float sWF0[63*WP];
    __shared__ float sWF1[63*WP];
    __shared__ float sPY[59*PYP];
    __shared__ float sPX[TS*PXP];
    __shared__ float sZY[TS*ZP];
    __shared__ float sZX[TS*ZP];
    __shared__ float sV2[TS*ZP];
    __shared__ float pa_y[63], pb_y[63], pa_x[63], pb_x[63];

    const int tid = threadIdx.x;
    const int bid = blockIdx.x;
    const int b   = bid >> 6;
    const int tl  = bid & 63;
    const int tyi = tl >> 3, txi = tl & 7;
    const int by0 = tyi*TS, bx0 = txi*TS;

    const int nbN = (tyi > 0)    ? bid - GT : -1;
    const int nbS = (tyi < GT-1) ? bid + GT : -1;
    const int nbW = (txi > 0)    ? bid - 1  : -1;
    const int nbE = (txi < GT-1) ? bid + 1  : -1;

    // ---- init LDS state ----
    for (int i = tid; i < 63*WP; i += NTH) { sWF0[i] = 0.f; sWF1[i] = 0.f; }
    for (int i = tid; i < 59*PYP; i += NTH) sPY[i] = 0.f;
    for (int i = tid; i < TS*PXP; i += NTH) sPX[i] = 0.f;
    for (int i = tid; i < TS*ZP; i += NTH) { sZY[i] = 0.f; sZX[i] = 0.f; }
    for (int i = tid; i < TS*TS; i += NTH) {
        int y = i/TS, x = i - y*TS;
        int cy = min(max(by0 + y - PMLW, 0), NVEL-1);
        int cx = min(max(bx0 + x - PMLW, 0), NVEL-1);
        float vv = v[cy*NVEL + cx];
        sV2[y*ZP + x] = vv*vv*(float)(0.0008*0.0008);
    }
    if (tid < 63) {
        const float smax = (float)(3.0*2600.0*6.907755278982137/160.0);
        {
            float g = (float)(by0 + tid - 4);
            float d = fmaxf(fminf(fmaxf((20.0f-g)/20.0f, 0.0f), 1.0f),
                            fminf(fmaxf((g-419.0f)/20.0f, 0.0f), 1.0f));
            float bb = expf(-smax*d*d*0.0008f);
            pb_y[tid] = bb; pa_y[tid] = bb - 1.0f;
        }
        {
            float g = (float)(bx0 + tid - 4);
            float d = fmaxf(fminf(fmaxf((20.0f-g)/20.0f, 0.0f), 1.0f),
                            fminf(fmaxf((g-419.0f)/20.0f, 0.0f), 1.0f));
            float bb = expf(-smax*d*d*0.0008f);
            pb_x[tid] = bb; pa_x[tid] = bb - 1.0f;
        }
    }

    const int sy = sloc[b*2]   + PMLW;
    const int sx = sloc[b*2+1] + PMLW;
    const int sci = (sy >= by0 && sy < by0+TS && sx >= bx0 && sx < bx0+TS)
                    ? (sy-by0)*TS + (sx-bx0) : -1;
    __syncthreads();

    float* cur = sWF0;
    float* nxt = sWF1;

    for (int t = 0; t < NT; ++t) {
        // ---- phase 1: psi update (incl. recomputed halo rows/cols) ----
        for (int i = tid; i < 59*TS; i += NTH) {
            int ly = i/TS, x = i - ly*TS;          // y = ly-2
            int wi = (ly+2)*WP + (x+4);
            float d1 = (cur[wi-2*WP] - cur[wi+2*WP]
                        + 8.f*(cur[wi+WP] - cur[wi-WP])) * C1f;
            int gy = by0 + ly - 2;
            float val = 0.f;
            if (gy >= 0 && gy < NSIDE)
                val = pb_y[ly+2]*sPY[ly*PYP + x] + pa_y[ly+2]*d1;
            sPY[ly*PYP + x] = val;
        }
        for (int i = tid; i < TS*59; i += NTH) {
            int y = i/59, lx = i - y*59;           // x = lx-2
            int wi = (y+4)*WP + (lx+2);
            float d1 = (cur[wi-2] - cur[wi+2]
                        + 8.f*(cur[wi+1] - cur[wi-1])) * C1f;
            int gx = bx0 + lx - 2;
            float val = 0.f;
            if (gx >= 0 && gx < NSIDE)
                val = pb_x[lx+2]*sPX[y*PXP + lx] + pa_x[lx+2]*d1;
            sPX[y*PXP + lx] = val;
        }
        __syncthreads();

        // ---- phase 2: interior update (+ fused source) ----
        for (int i = tid; i < TS*TS; i += NTH) {
            int y = i/TS, x = i - y*TS;
            int wi = (y+4)*WP + (x+4);
            float wc = cur[wi];
            float d2y = (-(cur[wi-2*WP] + cur[wi+2*WP])
                         + 16.f*(cur[wi-WP] + cur[wi+WP]) - 30.f*wc) * C2f
                      + (sPY[y*PYP+x] - sPY[(y+4)*PYP+x]
                         + 8.f*(sPY[(y+3)*PYP+x] - sPY[(y+1)*PYP+x])) * C1f;
            float d2x = (-(cur[wi-2] + cur[wi+2])
                         + 16.f*(cur[wi-1] + cur[wi+1]) - 30.f*wc) * C2f
                      + (sPX[y*PXP+x] - sPX[y*PXP+x+4]
                         + 8.f*(sPX[y*PXP+x+3] - sPX[y*PXP+x+1])) * C1f;
            int zi = y*ZP + x;
            float zy = pb_y[y+4]*sZY[zi] + pa_y[y+4]*d2y;
            float zx = pb_x[x+4]*sZX[zi] + pa_x[x+4]*d2x;
            sZY[zi] = zy; sZX[zi] = zx;
            float wnew = sV2[zi]*(d2y + zy + d2x + zx) + 2.f*wc - nxt[wi];
            if (i == sci) wnew += sV2[zi] * amp[b*NT + t];
            nxt[wi] = wnew;
        }
        __syncthreads();

        // ---- phase 3: record receivers of this step ----
        if (tid < NREC) {
            int ry = rloc[(b*NREC+tid)*2]   + PMLW;
            int rx = rloc[(b*NREC+tid)*2+1] + PMLW;
            if (ry >= by0 && ry < by0+TS && rx >= bx0 && rx < bx0+TS)
                out[(b*NREC+tid)*NT + t] = nxt[(ry-by0+4)*WP + (rx-bx0+4)];
        }

        if (t < NT-1) {
            int par = t & 1;
            // ---- export my boundary strips (agent-scope stores) ----
            float* sb = strips + (size_t)(par*256 + bid)*880;
            for (int i = tid; i < 880; i += NTH) {
                int e = i/220, j = i - e*220, r = j/55, c = j - r*55;
                float val;
                if      (e == 0) val = nxt[(r+4)*WP + c+4];        // rows 0..3
                else if (e == 1) val = nxt[(55+r)*WP + c+4];       // rows 51..54
                else if (e == 2) val = nxt[(c+4)*WP + r+4];        // cols 0..3
                else             val = nxt[(c+4)*WP + 55+r];       // cols 51..54
                __hip_atomic_store(&sb[i], val, __ATOMIC_RELAXED, __HIP_MEMORY_SCOPE_AGENT);
            }
            __syncthreads();
            if (tid == 0) {
                __threadfence();
                __hip_atomic_store(&flags[bid], t+1, __ATOMIC_RELEASE, __HIP_MEMORY_SCOPE_AGENT);
            }
            // ---- wait for the 4 edge neighbors (bounded spin) ----
            if (tid < 4) {
                int nb = (tid==0) ? nbN : (tid==1) ? nbS : (tid==2) ? nbW : nbE;
                if (nb >= 0) {
                    long spin = 0;
                    while (__hip_atomic_load(&flags[nb], __ATOMIC_ACQUIRE,
                                             __HIP_MEMORY_SCOPE_AGENT) <= t
                           && spin < 100000000L) {
                        __builtin_amdgcn_s_sleep(1);
                        ++spin;
                    }
                }
            }
            __syncthreads();
            // ---- import neighbor strips into my wf halo ----
            const float* sbase = strips + (size_t)par*256*880;
            for (int i = tid; i < 880; i += NTH) {
                int e = i/220, j = i - e*220, r = j/55, c = j - r*55;
                if (e == 0) { if (nbN >= 0)
                    nxt[r*WP + c+4] = __hip_atomic_load(&sbase[nbN*880 + 1*220 + j],
                                      __ATOMIC_RELAXED, __HIP_MEMORY_SCOPE_AGENT); }
                else if (e == 1) { if (nbS >= 0)
                    nxt[(59+r)*WP + c+4] = __hip_atomic_load(&sbase[nbS*880 + 0*220 + j],
                                      __ATOMIC_RELAXED, __HIP_MEMORY_SCOPE_AGENT); }
                else if (e == 2) { if (nbW >= 0)
                    nxt[(c+4)*WP + r] = __hip_atomic_load(&sbase[nbW*880 + 3*220 + j],
                                      __ATOMIC_RELAXED, __HIP_MEMORY_SCOPE_AGENT); }
                else { if (nbE >= 0)
                    nxt[(c+4)*WP + 59+r] = __hip_atomic_load(&sbase[nbE*880 + 2*220 + j],
                                      __ATOMIC_RELAXED, __HIP_MEMORY_SCOPE_AGENT); }
            }
        }
        __syncthreads();
        float* tmp = cur; cur = nxt; nxt = tmp;
    }
}

extern "C" void kernel_launch(void* const* d_in, const int* in_sizes, int n_in,
                              void* d_out, int out_size, void* d_ws, size_t ws_size,
                              hipStream_t stream) {
    const float* v    = (const float*)d_in[0];
    const float* amp  = (const float*)d_in[1];
    const int*   sloc = (const int*)d_in[2];
    const int*   rloc = (const int*)d_in[3];
    float* out = (float*)d_out;

    int*   flags  = (int*)d_ws;
    float* strips = (float*)((char*)d_ws + 1024);

    hipMemsetAsync(flags, 0, 1024, stream);
    kWave<<<256, NTH, 0, stream>>>(v, amp, sloc, rloc, out, flags, strips);
}

// Round 4
// 746.341 us; speedup vs baseline: 2.0861x; 1.8674x over previous
//
#include <hip/hip_runtime.h>

#define NVEL  400
#define PMLW  20
#define NSIDE 440
#define BATCH 4
#define NT    100
#define NREC  100

#define TS 55              // tile side; 8x8 tiles x 4 batches = 256 blocks (1/CU)
#define GT 8
#define WP 65              // wf LDS pitch (odd -> no stride-64 bank aliasing)
#define PYP 56             // psiy rows -2..56 (59) x cols 0..54
#define PXP 60             // psix rows 0..54 x cols -2..56 (59)
#define ZP  56

#define C1f (1.0f/48.0f)   // 1/(12*dh)
#define C2f (1.0f/192.0f)  // 1/(12*dh*dh)
#define NTH 1024

#define WIDX(y,x) (((y)+4)*WP + ((x)+4))

__global__ __launch_bounds__(NTH, 1) void kWave(
    const float* __restrict__ v, const float* __restrict__ amp,
    const int* __restrict__ sloc, const int* __restrict__ rloc,
    float* __restrict__ out, int* __restrict__ flags, float* __restrict__ strips)
{
    __shared__ float sWF0[63*WP], sWF1[63*WP];
    __shared__ float sPY[59*PYP];
    __shared__ float sPX[TS*PXP];
    __shared__ float sZY[TS*ZP], sZX[TS*ZP], sV2[TS*ZP];
    __shared__ float pa_y[63], pb_y[63], pa_x[63], pb_x[63];

    const int tid = threadIdx.x;
    const int bid = blockIdx.x;
    const int b   = bid >> 6;
    const int tl  = bid & 63;
    const int tyi = tl >> 3, txi = tl & 7;
    const int by0 = tyi*TS, bx0 = txi*TS;
    const int nbN = (tyi > 0)    ? bid - GT : -1;
    const int nbS = (tyi < GT-1) ? bid + GT : -1;
    const int nbW = (txi > 0)    ? bid - 1  : -1;
    const int nbE = (txi < GT-1) ? bid + 1  : -1;

    // ---- init LDS state ----
    for (int i = tid; i < 63*WP; i += NTH) { sWF0[i] = 0.f; sWF1[i] = 0.f; }
    for (int i = tid; i < 59*PYP; i += NTH) sPY[i] = 0.f;
    for (int i = tid; i < TS*PXP; i += NTH) sPX[i] = 0.f;
    for (int i = tid; i < TS*ZP; i += NTH) { sZY[i] = 0.f; sZX[i] = 0.f; }
    for (int i = tid; i < TS*TS; i += NTH) {
        int y = i/TS, x = i - y*TS;
        int cy = min(max(by0 + y - PMLW, 0), NVEL-1);
        int cx = min(max(bx0 + x - PMLW, 0), NVEL-1);
        float vv = v[cy*NVEL + cx];
        sV2[y*ZP + x] = vv*vv*(float)(0.0008*0.0008);
    }
    if (tid < 63) {
        const float smax = (float)(3.0*2600.0*6.907755278982137/160.0);
        float gy = (float)(by0 + tid - 4);
        float dy = fmaxf(fminf(fmaxf((20.f-gy)/20.f,0.f),1.f),
                         fminf(fmaxf((gy-419.f)/20.f,0.f),1.f));
        float bby = expf(-smax*dy*dy*0.0008f);
        pb_y[tid] = bby; pa_y[tid] = bby - 1.f;
        float gx = (float)(bx0 + tid - 4);
        float dx = fmaxf(fminf(fmaxf((20.f-gx)/20.f,0.f),1.f),
                         fminf(fmaxf((gx-419.f)/20.f,0.f),1.f));
        float bbx = expf(-smax*dx*dx*0.0008f);
        pb_x[tid] = bbx; pa_x[tid] = bbx - 1.f;
    }

    const int sly = sloc[b*2]   + PMLW - by0;   // source local coords (may be off-tile)
    const int slx = sloc[b*2+1] + PMLW - bx0;

    // receiver precompute (one per thread, tid<100)
    int rofs = -1, rIdx = 0;
    if (tid < NREC) {
        int gry = rloc[(b*NREC+tid)*2]   + PMLW;
        int grx = rloc[(b*NREC+tid)*2+1] + PMLW;
        if (gry >= by0 && gry < by0+TS && grx >= bx0 && grx < bx0+TS) {
            rofs = (b*NREC+tid)*NT;
            rIdx = WIDX(gry-by0, grx-bx0);
        }
    }

    // import/export descriptors. Slots: 0=rows0..3, 1=rows51..54 (c-fast),
    // 2=cols0..3, 3=cols51..54 (r-fast). 220 elems each.
    int imp_nb = -1, imp_src = 0, imp_dst = 0, exp_src = 0;
    if (tid < 880) {
        int e = tid/220, j = tid - e*220;
        if (e == 0)      { int r=j/55, c=j-55*r; imp_nb=nbN; imp_src=1*220+j; imp_dst=WIDX(r-4,c);   exp_src=WIDX(r,c); }
        else if (e == 1) { int r=j/55, c=j-55*r; imp_nb=nbS; imp_src=0*220+j; imp_dst=WIDX(55+r,c);  exp_src=WIDX(51+r,c); }
        else if (e == 2) { int r=j&3,  c=j>>2;   imp_nb=nbW; imp_src=3*220+j; imp_dst=WIDX(c,r-4);   exp_src=WIDX(c,r); }
        else             { int r=j&3,  c=j>>2;   imp_nb=nbE; imp_src=2*220+j; imp_dst=WIDX(c,55+r);  exp_src=WIDX(c,51+r); }
    }
    __syncthreads();

    float* cur = sWF0;
    float* nxt = sWF1;

#define PHASE2_BODY(yy, xx) {                                                   \
    int y = (yy), x = (xx);                                                     \
    int w = WIDX(y, x);                                                         \
    float wc = cur[w];                                                          \
    float d2y = (-(cur[w-2*WP] + cur[w+2*WP])                                   \
                 + 16.f*(cur[w-WP] + cur[w+WP]) - 30.f*wc) * C2f                \
              + (sPY[y*PYP+x] - sPY[(y+4)*PYP+x]                                \
                 + 8.f*(sPY[(y+3)*PYP+x] - sPY[(y+1)*PYP+x])) * C1f;            \
    float d2x = (-(cur[w-2] + cur[w+2])                                         \
                 + 16.f*(cur[w-1] + cur[w+1]) - 30.f*wc) * C2f                  \
              + (sPX[y*PXP+x] - sPX[y*PXP+x+4]                                  \
                 + 8.f*(sPX[y*PXP+x+3] - sPX[y*PXP+x+1])) * C1f;                \
    int zi = y*ZP + x;                                                          \
    float zy = pb_y[y+4]*sZY[zi] + pa_y[y+4]*d2y;                               \
    float zx = pb_x[x+4]*sZX[zi] + pa_x[x+4]*d2x;                               \
    sZY[zi] = zy; sZX[zi] = zx;                                                 \
    float wnew = sV2[zi]*(d2y + zy + d2x + zx) + 2.f*wc - nxt[w];               \
    if (y == sly && x == slx) wnew += sV2[zi] * amp[b*NT + t];                  \
    nxt[w] = wnew; }

    for (int t = 0; t < NT; ++t) {
        // ---- A: psi-core (rows/cols 2..52, owned wf only) ----
        for (int i = tid; i < 51*TS; i += NTH) {
            int r = i/TS; int x = i - r*TS; r += 2;
            int w = WIDX(r, x);
            float d1 = (cur[w-2*WP] - cur[w+2*WP] + 8.f*(cur[w+WP] - cur[w-WP]))*C1f;
            int pi = (r+2)*PYP + x;
            sPY[pi] = pb_y[r+4]*sPY[pi] + pa_y[r+4]*d1;
        }
        for (int i = tid; i < 51*TS; i += NTH) {
            int y = i/51; int c = i - y*51 + 2;
            int w = WIDX(y, c);
            float d1 = (cur[w-2] - cur[w+2] + 8.f*(cur[w+1] - cur[w-1]))*C1f;
            int pi = y*PXP + c + 2;
            sPX[pi] = pb_x[c+4]*sPX[pi] + pa_x[c+4]*d1;
        }
        __syncthreads();

        // ---- B: core interior update [4,50]^2  (+ overlapped halo import) ----
        for (int i = tid; i < 47*47; i += NTH) {
            int yy = i/47; int xx = i - yy*47 + 4; yy += 4;
            PHASE2_BODY(yy, xx)
        }
        if (t > 0 && imp_nb >= 0) {
            int spin = 0;
            while (__hip_atomic_load(&flags[imp_nb], __ATOMIC_RELAXED,
                                     __HIP_MEMORY_SCOPE_AGENT) < t
                   && spin < 2000000) { __builtin_amdgcn_s_sleep(1); ++spin; }
            asm volatile("" ::: "memory");
            cur[imp_dst] = __hip_atomic_load(
                &strips[(size_t)(((t-1)&1)*256 + imp_nb)*880 + imp_src],
                __ATOMIC_RELAXED, __HIP_MEMORY_SCOPE_AGENT);
        }
        __syncthreads();

        // ---- C: psi-rim (rows/cols -2..1 and 53..56; needs imported halo) ----
        if (tid < 440) {
            int k = tid/55; int x = tid - 55*k;
            int r = (k < 4) ? (k-2) : (k+49);
            int w = WIDX(r, x);
            float d1 = (cur[w-2*WP] - cur[w+2*WP] + 8.f*(cur[w+WP] - cur[w-WP]))*C1f;
            int gy = by0 + r;
            int pi = (r+2)*PYP + x;
            float val = 0.f;
            if (gy >= 0 && gy < NSIDE) val = pb_y[r+4]*sPY[pi] + pa_y[r+4]*d1;
            sPY[pi] = val;
        } else if (tid < 880) {
            int q = tid - 440;
            int k = q/55; int y = q - 55*k;
            int c = (k < 4) ? (k-2) : (k+49);
            int w = WIDX(y, c);
            float d1 = (cur[w-2] - cur[w+2] + 8.f*(cur[w+1] - cur[w-1]))*C1f;
            int gx = bx0 + c;
            int pi = y*PXP + c + 2;
            float val = 0.f;
            if (gx >= 0 && gx < NSIDE) val = pb_x[c+4]*sPX[pi] + pa_x[c+4]*d1;
            sPX[pi] = val;
        }
        __syncthreads();

        // ---- D: rim interior update (816 cells) ----
        if (tid < 816) {
            int yy, xx;
            if (tid < 440) { int k = tid/55; xx = tid - 55*k; yy = (k < 4) ? k : (k+47); }
            else { int q = tid - 440; int r8 = q >> 3; int c8 = q & 7;
                   yy = r8 + 4; xx = (c8 < 4) ? c8 : (c8+47); }
            PHASE2_BODY(yy, xx)
        }
        __syncthreads();

        // ---- E: record receivers + export strips + release flag ----
        if (rofs >= 0) out[rofs + t] = nxt[rIdx];
        if (t < NT-1) {
            if (tid < 880)
                __hip_atomic_store(&strips[(size_t)((t&1)*256 + bid)*880 + tid],
                                   nxt[exp_src], __ATOMIC_RELAXED,
                                   __HIP_MEMORY_SCOPE_AGENT);
            __builtin_amdgcn_s_waitcnt(0);   // drain this wave's stores
            __syncthreads();                 // all waves' stores at coherence point
            if (tid == 0)
                __hip_atomic_store(&flags[bid], t+1, __ATOMIC_RELEASE,
                                   __HIP_MEMORY_SCOPE_AGENT);
        }
        float* tmp = cur; cur = nxt; nxt = tmp;
    }
#undef PHASE2_BODY
}

extern "C" void kernel_launch(void* const* d_in, const int* in_sizes, int n_in,
                              void* d_out, int out_size, void* d_ws, size_t ws_size,
                              hipStream_t stream) {
    const float* v    = (const float*)d_in[0];
    const float* amp  = (const float*)d_in[1];
    const int*   sloc = (const int*)d_in[2];
    const int*   rloc = (const int*)d_in[3];
    float* out = (float*)d_out;

    int*   flags  = (int*)d_ws;
    float* strips = (float*)((char*)d_ws + 1024);

    hipMemsetAsync(flags, 0, 1024, stream);
    kWave<<<256, NTH, 0, stream>>>(v, amp, sloc, rloc, out, flags, strips);
}